// Round 2
// baseline (2750.229 us; speedup 1.0000x reference)
//
#include <hip/hip_runtime.h>
#include <hip/hip_bf16.h>
#include <math.h>

// Sinkhorn distance, B=4, P1=P2=2048, D=64, EPS=0.1, 100 iterations.
// d_out layout: cost[4] | pi[4*2048*2048] | C[4*2048*2048]
//
// Structure (v2):
//  - C computed once (squared-difference tiles). NO C^T copy.
//  - sweep_kernel: each block owns 16 rows of C in registers (thread t holds
//    cols [8t,8t+8)). Phase A: exact row-LSE -> u (u_{k+1} depends only on
//    v_k; the u/eps term cancels algebraically). Phase B: thread-local
//    column-LSE partials over the 16 rows using the fresh u -> (m,s) per col.
//  - reduce_v: merges 128 block-partials per column (online LSE) -> v.
//  - Epilogue: pi = exp((u_i + v_j - C_ij)/eps), cost = sum(pi*C).
// Per-iter traffic: 67MB C (L3-resident) + 16MB partials, vs 134MB in v1.
// Partials live in the dead pi output slot; u,v live in d_ws (final_pi reads
// them while overwriting pi, so they must not alias the pi region).

#define P 2048
#define D 64
#define B 4
#define EPS 0.1f
// (1/eps) * log2(e): fold eps-divide and exp->exp2 into one scale
#define KS 14.426950408889634f
// eps * ln(2): convert log2-domain LSE back to natural-log domain, times eps
#define EL2 0.06931471805599453f

#define EX2 __builtin_amdgcn_exp2f   // v_exp_f32 (exp2)
#define LG2 __builtin_amdgcn_logf    // v_log_f32 (log2)

// ---------------------------------------------------------------- cost matrix
// grid (32, 32, 4), block 256. 64x64 tile, 4x4 per thread.
__global__ __launch_bounds__(256) void cost_kernel(
    const float* __restrict__ X, const float* __restrict__ Y,
    float* __restrict__ C) {
  __shared__ float xs[64][65];
  __shared__ float ys[64][65];
  const int b = blockIdx.z;
  const int i0 = blockIdx.y * 64;
  const int j0 = blockIdx.x * 64;
  const float* Xb = X + ((size_t)b * P + i0) * D;
  const float* Yb = Y + ((size_t)b * P + j0) * D;
  const int t = threadIdx.x;
#pragma unroll
  for (int n = 0; n < 4; n++) {
    int e4 = t + n * 256;
    float4 xv = ((const float4*)Xb)[e4];
    float4 yv = ((const float4*)Yb)[e4];
    int r = e4 >> 4;
    int k = (e4 & 15) * 4;
    xs[r][k] = xv.x; xs[r][k + 1] = xv.y; xs[r][k + 2] = xv.z; xs[r][k + 3] = xv.w;
    ys[r][k] = yv.x; ys[r][k + 1] = yv.y; ys[r][k + 2] = yv.z; ys[r][k + 3] = yv.w;
  }
  __syncthreads();
  const int tx = t & 15;
  const int ty = t >> 4;
  float acc[4][4] = {};
#pragma unroll
  for (int k = 0; k < D; k++) {
    float a[4], bb[4];
#pragma unroll
    for (int r = 0; r < 4; r++) a[r] = xs[ty * 4 + r][k];
#pragma unroll
    for (int c = 0; c < 4; c++) bb[c] = ys[tx * 4 + c][k];
#pragma unroll
    for (int r = 0; r < 4; r++)
#pragma unroll
      for (int c = 0; c < 4; c++) {
        float d = a[r] - bb[c];
        acc[r][c] = fmaf(d, d, acc[r][c]);
      }
  }
#pragma unroll
  for (int r = 0; r < 4; r++) {
    float4 o = make_float4(acc[r][0], acc[r][1], acc[r][2], acc[r][3]);
    *(float4*)&C[((size_t)b * P + i0 + ty * 4 + r) * P + j0 + tx * 4] = o;
  }
}

// -------------------------------------------------------- fused u + v-partial
// grid 512 (= 8192 rows / 16), block 256 (4 waves). Block owns rows
// [16*bid, 16*bid+16); thread t owns cols [8t, 8t+8). Two groups of 8 rows
// to cap register pressure (64 C-regs live per group).
__global__ __launch_bounds__(256, 2) void sweep_kernel(
    const float* __restrict__ C, const float* __restrict__ v,
    float* __restrict__ u, float2* __restrict__ part, float elog) {
  const int bid = blockIdx.x;
  const int grow0 = bid * 16;
  const int b = grow0 >> 11;
  const int kb = bid & 127;          // block index within this batch (0..127)
  const int t = threadIdx.x;
  const int lane = t & 63;
  const int w = t >> 6;

  // v chunk for this thread's 8 columns, pre-scaled by KS
  float vvK[8];
  {
    const float4* vp = (const float4*)(v + ((size_t)b << 11) + t * 8);
    float4 a = vp[0], c4 = vp[1];
    vvK[0] = a.x * KS;  vvK[1] = a.y * KS;  vvK[2] = a.z * KS;  vvK[3] = a.w * KS;
    vvK[4] = c4.x * KS; vvK[5] = c4.y * KS; vvK[6] = c4.z * KS; vvK[7] = c4.w * KS;
  }

  float colm[8], cols[8];
#pragma unroll
  for (int j = 0; j < 8; j++) { colm[j] = -__builtin_inff(); cols[j] = 0.f; }

  __shared__ float redm[4][8];
  __shared__ float reds[4][8];

#pragma unroll
  for (int g = 0; g < 2; g++) {
    // ---- load 8 rows x 8 cols, pre-scaled by KS
    float cK[8][8];
    const float* Cb = C + ((size_t)(grow0 + g * 8)) * P + t * 8;
#pragma unroll
    for (int r = 0; r < 8; r++) {
      float4 a = *(const float4*)(Cb + (size_t)r * P);
      float4 q = *(const float4*)(Cb + (size_t)r * P + 4);
      cK[r][0] = a.x * KS; cK[r][1] = a.y * KS; cK[r][2] = a.z * KS; cK[r][3] = a.w * KS;
      cK[r][4] = q.x * KS; cK[r][5] = q.y * KS; cK[r][6] = q.z * KS; cK[r][7] = q.w * KS;
    }

    // ---- phase A: exact row LSE of z = vvK - cK  (log2 domain, pre-eps)
    float lm[8];
#pragma unroll
    for (int r = 0; r < 8; r++) {
      float m = vvK[0] - cK[r][0];
#pragma unroll
      for (int j = 1; j < 8; j++) m = fmaxf(m, vvK[j] - cK[r][j]);
#pragma unroll
      for (int off = 32; off; off >>= 1) m = fmaxf(m, __shfl_xor(m, off));
      lm[r] = m;
    }
    if (lane == 0) {
#pragma unroll
      for (int r = 0; r < 8; r++) redm[w][r] = lm[r];
    }
    __syncthreads();
    float bm[8];
#pragma unroll
    for (int r = 0; r < 8; r++)
      bm[r] = fmaxf(fmaxf(redm[0][r], redm[1][r]),
                    fmaxf(redm[2][r], redm[3][r]));
    float ls[8];
#pragma unroll
    for (int r = 0; r < 8; r++) {
      float s = 0.f;
#pragma unroll
      for (int j = 0; j < 8; j++) s += EX2(vvK[j] - cK[r][j] - bm[r]);
#pragma unroll
      for (int off = 32; off; off >>= 1) s += __shfl_xor(s, off);
      ls[r] = s;
    }
    if (lane == 0) {
#pragma unroll
      for (int r = 0; r < 8; r++) reds[w][r] = ls[r];
    }
    __syncthreads();
    float urK[8];  // u * KS (for phase B), plus write raw u
    float urr[8];
#pragma unroll
    for (int r = 0; r < 8; r++) {
      float S = (reds[0][r] + reds[1][r]) + (reds[2][r] + reds[3][r]);
      urr[r] = elog - EL2 * (bm[r] + LG2(S));
      urK[r] = urr[r] * KS;
    }
    if (t == 0) {
#pragma unroll
      for (int r = 0; r < 8; r++) u[grow0 + g * 8 + r] = urr[r];
    }

    // ---- phase B: thread-local column-LSE partial over these 8 rows
#pragma unroll
    for (int cc = 0; cc < 8; cc++) {
      float z[8];
#pragma unroll
      for (int r = 0; r < 8; r++) z[r] = urK[r] - cK[r][cc];
      float tm = z[0];
#pragma unroll
      for (int r = 1; r < 8; r++) tm = fmaxf(tm, z[r]);
      float M = fmaxf(colm[cc], tm);
      float s = 0.f;
#pragma unroll
      for (int r = 0; r < 8; r++) s += EX2(z[r] - M);
      cols[cc] = cols[cc] * EX2(colm[cc] - M) + s;  // exp2(-inf)=0 on g=0
      colm[cc] = M;
    }
    __syncthreads();  // protect redm/reds reuse across groups
  }

  // ---- write column partials: part[kb][gcol], gcol = b*2048 + 8t + cc
#pragma unroll
  for (int cc = 0; cc < 8; cc++) {
    part[(size_t)kb * (B * P) + (size_t)b * P + t * 8 + cc] =
        make_float2(colm[cc], cols[cc]);
  }
}

// --------------------------------------------------------- v partial merge
// 4 threads per column; each merges 32 of the 128 partials, then 2 shfl merges.
// grid 128, block 256.
__global__ __launch_bounds__(256) void reduce_v(
    const float2* __restrict__ part, float* __restrict__ v, float elog) {
  const int gtid = blockIdx.x * 256 + threadIdx.x;
  const int col = gtid >> 2;       // 0..8191
  const int seg = gtid & 3;
  const int k0 = seg * 32;
  float m = -__builtin_inff();
  float s = 0.f;
#pragma unroll 8
  for (int k = 0; k < 32; k++) {
    float2 p = part[(size_t)(k0 + k) * (B * P) + col];
    float M = fmaxf(m, p.x);
    s = s * EX2(m - M) + p.y * EX2(p.x - M);
    m = M;
  }
#pragma unroll
  for (int off = 1; off <= 2; off <<= 1) {
    float om = __shfl_xor(m, off);
    float os = __shfl_xor(s, off);
    float M = fmaxf(m, om);
    s = s * EX2(m - M) + os * EX2(om - M);
    m = M;
  }
  if (seg == 0) v[col] = elog - EL2 * (m + LG2(s));
}

// ------------------------------------------------------------------ epilogue
__global__ __launch_bounds__(256) void final_pi(
    const float* __restrict__ C, const float* __restrict__ u,
    const float* __restrict__ v, float* __restrict__ pi,
    float* __restrict__ cost) {
  const int row = blockIdx.x;
  const int b = row >> 11;
  const int t = threadIdx.x;
  const float4* cp = (const float4*)(C + (size_t)row * P);
  const float4* vp = (const float4*)(v + ((size_t)b << 11));
  float4* pp = (float4*)(pi + (size_t)row * P);
  const float ui = u[row];
  float acc = 0.f;
#pragma unroll
  for (int n = 0; n < 2; n++) {
    float4 c = cp[t + n * 256];
    float4 vv = vp[t + n * 256];
    float4 p;
    p.x = EX2((ui + vv.x - c.x) * KS);
    p.y = EX2((ui + vv.y - c.y) * KS);
    p.z = EX2((ui + vv.z - c.z) * KS);
    p.w = EX2((ui + vv.w - c.w) * KS);
    acc += p.x * c.x + p.y * c.y + p.z * c.z + p.w * c.w;
    pp[t + n * 256] = p;
  }
#pragma unroll
  for (int off = 32; off; off >>= 1) acc += __shfl_xor(acc, off);
  __shared__ float sa[4];
  if ((t & 63) == 0) sa[t >> 6] = acc;
  __syncthreads();
  if (t == 0) atomicAdd(cost + b, sa[0] + sa[1] + sa[2] + sa[3]);
}

// -------------------------------------------------------------------- launch
extern "C" void kernel_launch(void* const* d_in, const int* in_sizes, int n_in,
                              void* d_out, int out_size, void* d_ws,
                              size_t ws_size, hipStream_t stream) {
  const float* x = (const float*)d_in[0];
  const float* y = (const float*)d_in[1];
  float* out = (float*)d_out;
  float* cost = out;                          // [4]
  float* pi = out + 4;                        // [B*P*P], dead until epilogue
  float* Cmat = out + 4 + (size_t)B * P * P;  // [B*P*P]

  float2* part = (float2*)pi;                 // 128*8192 float2 = 8MB scratch
  float* u = (float*)d_ws;                    // [8192]
  float* v = u + B * P;                       // [8192]

  hipMemsetAsync(v, 0, B * P * sizeof(float), stream);
  hipMemsetAsync(cost, 0, 4 * sizeof(float), stream);

  dim3 cgrid(P / 64, P / 64, B);
  cost_kernel<<<cgrid, 256, 0, stream>>>(x, y, Cmat);

  const float elog = EPS * logf(1.0f / (float)P + 1e-8f);

  for (int it = 0; it < 100; it++) {
    sweep_kernel<<<B * P / 16, 256, 0, stream>>>(Cmat, v, u, part, elog);
    reduce_v<<<B * P * 4 / 256, 256, 0, stream>>>(part, v, elog);
  }

  final_pi<<<B * P, 256, 0, stream>>>(Cmat, u, v, pi, cost);
}